// Round 1
// baseline (330.551 us; speedup 1.0000x reference)
//
#include <hip/hip_runtime.h>

// Problem constants (from reference setup_inputs):
//   B=4, P=12000, C=64, NX=NY=512
//   in[0]: pillar_embeddings float32 [B,P,C]
//   in[1]: pillar_coords     int32   [B,P,2]  (ix, iy)
//   in[2]: pillar_mask       int32   [B,P]
//   out:   float32 [B, C, NY, NX]  (zero except out[b,:,iy,ix] = emb[b,p,:] for mask>0)
#define NXc 512
#define NYc 512
#define Bc  4
#define Pc  12000
#define Cc  64

// Kernel 1: zero the 256 MB output with vectorized grid-stride stores.
__global__ void bev_zero_kernel(float4* __restrict__ out, int n4) {
    int i = blockIdx.x * blockDim.x + threadIdx.x;
    int stride = gridDim.x * blockDim.x;
    const float4 z = make_float4(0.f, 0.f, 0.f, 0.f);
    for (; i < n4; i += stride) out[i] = z;
}

// Kernel 2: one wave per pillar; lane = channel. Coalesced 256 B embedding
// read per pillar; scattered 4 B store per (channel, cell). Cells are unique
// per batch (reference guarantees) so no write races.
__global__ void bev_scatter_kernel(const float* __restrict__ emb,
                                   const int* __restrict__ coords,
                                   const int* __restrict__ mask,
                                   float* __restrict__ out) {
    const int wavesPerBlock = blockDim.x >> 6;           // 64-lane waves
    const int pillar = blockIdx.x * wavesPerBlock + (threadIdx.x >> 6);
    const int lane = threadIdx.x & 63;                   // channel index (C=64)
    if (pillar >= Bc * Pc) return;
    if (mask[pillar] <= 0) return;                       // wave-uniform branch
    const int ix = coords[pillar * 2 + 0];
    const int iy = coords[pillar * 2 + 1];
    const int flat = iy * NXc + ix;                      // within [0, NX*NY)
    const int b = pillar / Pc;
    const float v = emb[(size_t)pillar * Cc + lane];     // coalesced 256 B/wave
    out[((size_t)b * Cc + lane) * (NYc * NXc) + flat] = v;
}

extern "C" void kernel_launch(void* const* d_in, const int* in_sizes, int n_in,
                              void* d_out, int out_size, void* d_ws, size_t ws_size,
                              hipStream_t stream) {
    const float* emb   = (const float*)d_in[0];
    const int* coords  = (const int*)d_in[1];
    const int* mask    = (const int*)d_in[2];
    float* out         = (float*)d_out;

    // 1) zero-fill output (out_size = 4*64*512*512 = 67,108,864 floats; /4 per float4)
    const int n4 = out_size >> 2;
    bev_zero_kernel<<<8192, 256, 0, stream>>>((float4*)out, n4);

    // 2) scatter: 4 waves (4 pillars) per 256-thread block
    const int nPillars = Bc * Pc;                        // 48000
    const int pillarsPerBlock = 256 / 64;                // 4
    const int grid = (nPillars + pillarsPerBlock - 1) / pillarsPerBlock;
    bev_scatter_kernel<<<grid, 256, 0, stream>>>(emb, coords, mask, out);
}

// Round 3
// 284.391 us; speedup vs baseline: 1.1623x; 1.1623x over previous
//
#include <hip/hip_runtime.h>

// B=4, P=12000, C=64, NX=NY=512
//   in[0]: pillar_embeddings float32 [B,P,C]
//   in[1]: pillar_coords     int32   [B,P,2]  (ix, iy)
//   in[2]: pillar_mask       int32   [B,P]
//   out:   float32 [B, C, NY, NX]
//
// Strategy: invert scatter -> gather. Phase 1 builds a cell->global-pillar
// map (4 MB in d_ws, -1 = empty). Phase 2 writes the whole output in ONE
// coalesced float4 pass, selecting emb value vs 0 per component. This
// avoids the zero-then-RMW-scatter double touch of the 256 MB output.
#define NXc 512
#define NYc 512
#define Bc  4
#define Pc  12000
#define Cc  64
#define CELLS (NXc * NYc)          // 262144 cells per batch
#define MAPN  (Bc * CELLS)         // 1,048,576 map entries (4 MB)

typedef float fv4 __attribute__((ext_vector_type(4)));   // native vec for NT store
typedef int   iv4 __attribute__((ext_vector_type(4)));

__global__ void map_init_kernel(iv4* __restrict__ map4) {
    const int i = blockIdx.x * blockDim.x + threadIdx.x;   // MAPN/4 threads
    iv4 m = {-1, -1, -1, -1};
    map4[i] = m;
}

__global__ void map_scatter_kernel(const int* __restrict__ coords,
                                   const int* __restrict__ mask,
                                   int* __restrict__ map) {
    const int p = blockIdx.x * blockDim.x + threadIdx.x;   // global pillar id
    if (p >= Bc * Pc) return;
    if (mask[p] <= 0) return;
    const int ix = coords[2 * p];
    const int iy = coords[2 * p + 1];
    const int b = p / Pc;
    map[b * CELLS + iy * NXc + ix] = p;    // cells unique per batch -> no race
}

// One thread owns 4 consecutive x at fixed (b, y) and loops over all 64
// channels: per c-iteration a wave stores 64 lanes x 16 B = 1 KB contiguous.
// Invalid map entries are routed to pillar 0 (one broadcast cache line) and
// zeroed by select -> no divergent loads.
__global__ void __launch_bounds__(256)
bev_gather_kernel(const float* __restrict__ emb,
                  const iv4* __restrict__ map4,
                  fv4* __restrict__ out4) {
    const int t = blockIdx.x * blockDim.x + threadIdx.x;   // MAPN/4 threads
    const int x4 = t & (NXc / 4 - 1);        // 0..127
    const int y  = (t >> 7) & (NYc - 1);     // 0..511
    const int b  = t >> 16;                  // 0..3
    const iv4 m = map4[t];                   // coalesced int4 map read

    const float* e0 = emb + (size_t)(m.x < 0 ? 0 : m.x) * Cc;
    const float* e1 = emb + (size_t)(m.y < 0 ? 0 : m.y) * Cc;
    const float* e2 = emb + (size_t)(m.z < 0 ? 0 : m.z) * Cc;
    const float* e3 = emb + (size_t)(m.w < 0 ? 0 : m.w) * Cc;

    fv4* op = out4 + (size_t)b * Cc * (CELLS / 4) + y * (NXc / 4) + x4;
    #pragma unroll 8
    for (int c = 0; c < Cc; ++c) {
        fv4 v;
        v.x = (m.x >= 0) ? e0[c] : 0.0f;
        v.y = (m.y >= 0) ? e1[c] : 0.0f;
        v.z = (m.z >= 0) ? e2[c] : 0.0f;
        v.w = (m.w >= 0) ? e3[c] : 0.0f;
        __builtin_nontemporal_store(v, op);  // write-only 256 MB: don't pollute LLC
        op += CELLS / 4;
    }
}

extern "C" void kernel_launch(void* const* d_in, const int* in_sizes, int n_in,
                              void* d_out, int out_size, void* d_ws, size_t ws_size,
                              hipStream_t stream) {
    const float* emb  = (const float*)d_in[0];
    const int* coords = (const int*)d_in[1];
    const int* mask   = (const int*)d_in[2];
    float* out        = (float*)d_out;
    int* map          = (int*)d_ws;          // 4 MB scratch

    map_init_kernel<<<MAPN / 4 / 256, 256, 0, stream>>>((iv4*)map);
    map_scatter_kernel<<<(Bc * Pc + 255) / 256, 256, 0, stream>>>(coords, mask, map);
    bev_gather_kernel<<<MAPN / 4 / 256, 256, 0, stream>>>(emb, (const iv4*)map,
                                                          (fv4*)out);
}